// Round 6
// baseline (670.669 us; speedup 1.0000x reference)
//
#include <hip/hip_runtime.h>
#include <stdint.h>

#define N_NODES  (1u << 20)      // 1048576
#define N_EDGES  (1u << 24)      // 16777216
#define N_GRAPHS 64
#define CHUNK    (N_NODES / N_GRAPHS)  // 16384
#define K_HOPS   4

#define NBUCKET  1024            // column buckets
#define CPB      1024            // cols per bucket
#define CAP      18432           // slots per bucket region (λ=16384, +16σ)

#define NBLK_SS  512             // scatter-sort blocks
#define TB_SS    1024            // scatter-sort threads
#define EPT      32              // edges per thread
#define EPB_SS   (TB_SS * EPT)   // 32768 edges per block

// ---------------------------------------------------------------------------
// Edge dtype detection: int64 little-endian with values < 2^20 has all-zero
// odd u32 words; int32 has random indices there. flag[0]=1 -> int64.
__global__ void detect_kernel(const uint32_t* __restrict__ ei, int* __restrict__ flag) {
    __shared__ int any_nz;
    if (threadIdx.x == 0) any_nz = 0;
    __syncthreads();
    int nz = 0;
    for (int i = threadIdx.x; i < 32768; i += blockDim.x)
        nz |= (ei[2 * i + 1] != 0u);
    if (nz) atomicOr(&any_nz, 1);
    __syncthreads();
    if (threadIdx.x == 0) flag[0] = any_nz ? 0 : 1;
}

__global__ void zero_int_kernel(int* __restrict__ p) {
    int i = blockIdx.x * blockDim.x + threadIdx.x;
    p[i] = 0;
}

// ---------------------------------------------------------------------------
// Per-block LDS counting sort by bucket, then coalesced run write-out.
__global__ __launch_bounds__(TB_SS, 4)
void scatter_sort_kernel(const void* __restrict__ ei, const int* __restrict__ flag,
                         int* __restrict__ cursor, uint32_t* __restrict__ packed) {
    __shared__ uint32_t sorted[EPB_SS];   // 128 KB
    __shared__ int h[NBUCKET];            // 4 KB
    __shared__ int o[NBUCKET];            // 4 KB (scan, then bumped by scatter)
    __shared__ int ostart[NBUCKET];       // 4 KB (stable run starts)
    __shared__ int gbase[NBUCKET];        // 4 KB
    int blk = blockIdx.x, tid = threadIdx.x;
    h[tid] = 0;
    __syncthreads();
    size_t base = (size_t)blk * EPB_SS;
    int is64 = flag[0];
    uint32_t c_[EPT];

    // Phase A: load cols, histogram buckets.
    if (is64) {
        const unsigned long long* cp = (const unsigned long long*)ei + N_EDGES + base;
        #pragma unroll
        for (int it = 0; it < EPT / 4; ++it) {
            size_t i = (size_t)it * (TB_SS * 4) + (size_t)tid * 4;
            ulonglong2 a = *(const ulonglong2*)(cp + i);
            ulonglong2 b2 = *(const ulonglong2*)(cp + i + 2);
            c_[it * 4 + 0] = (uint32_t)a.x;  c_[it * 4 + 1] = (uint32_t)a.y;
            c_[it * 4 + 2] = (uint32_t)b2.x; c_[it * 4 + 3] = (uint32_t)b2.y;
            atomicAdd(&h[c_[it * 4 + 0] >> 10], 1);
            atomicAdd(&h[c_[it * 4 + 1] >> 10], 1);
            atomicAdd(&h[c_[it * 4 + 2] >> 10], 1);
            atomicAdd(&h[c_[it * 4 + 3] >> 10], 1);
        }
    } else {
        const uint32_t* cp = (const uint32_t*)ei + N_EDGES + base;
        #pragma unroll
        for (int it = 0; it < EPT / 4; ++it) {
            size_t i = (size_t)it * (TB_SS * 4) + (size_t)tid * 4;
            uint4 a = *(const uint4*)(cp + i);
            c_[it * 4 + 0] = a.x; c_[it * 4 + 1] = a.y;
            c_[it * 4 + 2] = a.z; c_[it * 4 + 3] = a.w;
            atomicAdd(&h[a.x >> 10], 1);
            atomicAdd(&h[a.y >> 10], 1);
            atomicAdd(&h[a.z >> 10], 1);
            atomicAdd(&h[a.w >> 10], 1);
        }
    }
    __syncthreads();

    // Phase B: wave 0 exclusive-scans h[1024] -> o/ostart.
    if (tid < 64) {
        int b16 = tid * 16;
        int s = 0;
        #pragma unroll
        for (int j = 0; j < 16; ++j) s += h[b16 + j];
        int v = s;
        #pragma unroll
        for (int off = 1; off < 64; off <<= 1) {
            int up = __shfl_up(v, off, 64);
            if (tid >= off) v += up;
        }
        int run = v - s;  // exclusive
        #pragma unroll
        for (int j = 0; j < 16; ++j) {
            o[b16 + j] = run;
            ostart[b16 + j] = run;
            run += h[b16 + j];
        }
    }
    __syncthreads();

    // Per-bucket global reserve (1 atomic per bucket per block).
    gbase[tid] = atomicAdd(&cursor[tid], h[tid]);

    // Phase C: load rows, scatter packed entries into LDS sorted buffer.
    if (is64) {
        const unsigned long long* rp = (const unsigned long long*)ei + base;
        #pragma unroll
        for (int it = 0; it < EPT / 4; ++it) {
            size_t i = (size_t)it * (TB_SS * 4) + (size_t)tid * 4;
            ulonglong2 a = *(const ulonglong2*)(rp + i);
            ulonglong2 b2 = *(const ulonglong2*)(rp + i + 2);
            uint32_t r0 = (uint32_t)a.x, r1 = (uint32_t)a.y;
            uint32_t r2 = (uint32_t)b2.x, r3 = (uint32_t)b2.y;
            { uint32_t c = c_[it * 4 + 0]; int pos = atomicAdd(&o[c >> 10], 1); sorted[pos] = (r0 << 10) | (c & 1023u); }
            { uint32_t c = c_[it * 4 + 1]; int pos = atomicAdd(&o[c >> 10], 1); sorted[pos] = (r1 << 10) | (c & 1023u); }
            { uint32_t c = c_[it * 4 + 2]; int pos = atomicAdd(&o[c >> 10], 1); sorted[pos] = (r2 << 10) | (c & 1023u); }
            { uint32_t c = c_[it * 4 + 3]; int pos = atomicAdd(&o[c >> 10], 1); sorted[pos] = (r3 << 10) | (c & 1023u); }
        }
    } else {
        const uint32_t* rp = (const uint32_t*)ei + base;
        #pragma unroll
        for (int it = 0; it < EPT / 4; ++it) {
            size_t i = (size_t)it * (TB_SS * 4) + (size_t)tid * 4;
            uint4 a = *(const uint4*)(rp + i);
            { uint32_t c = c_[it * 4 + 0]; int pos = atomicAdd(&o[c >> 10], 1); sorted[pos] = (a.x << 10) | (c & 1023u); }
            { uint32_t c = c_[it * 4 + 1]; int pos = atomicAdd(&o[c >> 10], 1); sorted[pos] = (a.y << 10) | (c & 1023u); }
            { uint32_t c = c_[it * 4 + 2]; int pos = atomicAdd(&o[c >> 10], 1); sorted[pos] = (a.z << 10) | (c & 1023u); }
            { uint32_t c = c_[it * 4 + 3]; int pos = atomicAdd(&o[c >> 10], 1); sorted[pos] = (a.w << 10) | (c & 1023u); }
        }
    }
    __syncthreads();

    // Phase D: write-out. Wave w copies buckets [w*64, w*64+64); runs contiguous.
    int wave = tid >> 6, lane = tid & 63;
    for (int k = 0; k < NBUCKET / 16; ++k) {
        int b = wave * (NBUCKET / 16) + k;
        int st = ostart[b];
        int len = o[b] - st;
        int gb = gbase[b];
        if (gb + len > CAP) len = CAP - gb > 0 ? CAP - gb : 0;
        uint32_t* dst = packed + (size_t)b * CAP + gb;
        for (int j = lane; j < len; j += 64)
            dst[j] = sorted[st + j];
    }
}

// ---------------------------------------------------------------------------
// Per-bucket degree -> dinv, fused with z0 = dinv * x. Batched 16 edges/thread.
__global__ __launch_bounds__(512)
void degdinv_kernel(const uint32_t* __restrict__ packed, const int* __restrict__ cursor,
                    const float* __restrict__ x,
                    float* __restrict__ dinv, float* __restrict__ z) {
    __shared__ int h[CPB];
    int b = blockIdx.x, tid = threadIdx.x;
    for (int l = tid; l < CPB; l += 512) h[l] = 0;
    __syncthreads();
    int cnt = cursor[b]; if (cnt > CAP) cnt = CAP;
    const uint32_t* seg = packed + (size_t)b * CAP;
    const uint4* seg4 = (const uint4*)seg;
    int nfull = cnt >> 13;  // batches of 8192 edges (2048 uint4)
    for (int it = 0; it < nfull; ++it) {
        int base = (it << 11) + tid;
        uint4 a0 = seg4[base];
        uint4 a1 = seg4[base + 512];
        uint4 a2 = seg4[base + 1024];
        uint4 a3 = seg4[base + 1536];
        atomicAdd(&h[a0.x & 1023u], 1); atomicAdd(&h[a0.y & 1023u], 1);
        atomicAdd(&h[a0.z & 1023u], 1); atomicAdd(&h[a0.w & 1023u], 1);
        atomicAdd(&h[a1.x & 1023u], 1); atomicAdd(&h[a1.y & 1023u], 1);
        atomicAdd(&h[a1.z & 1023u], 1); atomicAdd(&h[a1.w & 1023u], 1);
        atomicAdd(&h[a2.x & 1023u], 1); atomicAdd(&h[a2.y & 1023u], 1);
        atomicAdd(&h[a2.z & 1023u], 1); atomicAdd(&h[a2.w & 1023u], 1);
        atomicAdd(&h[a3.x & 1023u], 1); atomicAdd(&h[a3.y & 1023u], 1);
        atomicAdd(&h[a3.z & 1023u], 1); atomicAdd(&h[a3.w & 1023u], 1);
    }
    int nv = cnt >> 2;
    for (int g = (nfull << 11) + tid; g < nv; g += 512) {
        uint4 v = *(const uint4*)(seg + g * 4);
        atomicAdd(&h[v.x & 1023u], 1);
        atomicAdd(&h[v.y & 1023u], 1);
        atomicAdd(&h[v.z & 1023u], 1);
        atomicAdd(&h[v.w & 1023u], 1);
    }
    int t = nv * 4 + tid;
    if (t < cnt) atomicAdd(&h[seg[t] & 1023u], 1);
    __syncthreads();
    for (int l = tid; l < CPB; l += 512) {
        int v = b * CPB + l;
        float d = (float)(1.0 / sqrt((double)(h[l] + 1)));  // +1 self loop
        dinv[v] = d;
        z[v] = d * x[v];
    }
}

// ---------------------------------------------------------------------------
// Bucketed hop, batched 16 edges/thread for memory-level parallelism:
// load 4x uint4 (independent), issue all 16 z-gathers, then 16 LDS adds.
__global__ __launch_bounds__(512)
void hop_kernel(const uint32_t* __restrict__ packed, const int* __restrict__ cursor,
                const float* __restrict__ z, const float* __restrict__ dinv,
                float* __restrict__ out, int mode) {
    __shared__ float facc[CPB];
    int b = blockIdx.x, tid = threadIdx.x;
    for (int l = tid; l < CPB; l += 512) facc[l] = 0.0f;
    __syncthreads();
    int cnt = cursor[b]; if (cnt > CAP) cnt = CAP;
    const uint32_t* seg = packed + (size_t)b * CAP;
    const uint4* seg4 = (const uint4*)seg;
    int nfull = cnt >> 13;  // batches of 8192 edges (2048 uint4)
    for (int it = 0; it < nfull; ++it) {
        int base = (it << 11) + tid;
        uint4 a0 = seg4[base];
        uint4 a1 = seg4[base + 512];
        uint4 a2 = seg4[base + 1024];
        uint4 a3 = seg4[base + 1536];
        float z00 = z[a0.x >> 10], z01 = z[a0.y >> 10], z02 = z[a0.z >> 10], z03 = z[a0.w >> 10];
        float z10 = z[a1.x >> 10], z11 = z[a1.y >> 10], z12 = z[a1.z >> 10], z13 = z[a1.w >> 10];
        float z20 = z[a2.x >> 10], z21 = z[a2.y >> 10], z22 = z[a2.z >> 10], z23 = z[a2.w >> 10];
        float z30 = z[a3.x >> 10], z31 = z[a3.y >> 10], z32 = z[a3.z >> 10], z33 = z[a3.w >> 10];
        atomicAdd(&facc[a0.x & 1023u], z00); atomicAdd(&facc[a0.y & 1023u], z01);
        atomicAdd(&facc[a0.z & 1023u], z02); atomicAdd(&facc[a0.w & 1023u], z03);
        atomicAdd(&facc[a1.x & 1023u], z10); atomicAdd(&facc[a1.y & 1023u], z11);
        atomicAdd(&facc[a1.z & 1023u], z12); atomicAdd(&facc[a1.w & 1023u], z13);
        atomicAdd(&facc[a2.x & 1023u], z20); atomicAdd(&facc[a2.y & 1023u], z21);
        atomicAdd(&facc[a2.z & 1023u], z22); atomicAdd(&facc[a2.w & 1023u], z23);
        atomicAdd(&facc[a3.x & 1023u], z30); atomicAdd(&facc[a3.y & 1023u], z31);
        atomicAdd(&facc[a3.z & 1023u], z32); atomicAdd(&facc[a3.w & 1023u], z33);
    }
    int nv = cnt >> 2;
    for (int g = (nfull << 11) + tid; g < nv; g += 512) {
        uint4 v = *(const uint4*)(seg + g * 4);
        float z0 = z[v.x >> 10];
        float z1 = z[v.y >> 10];
        float z2 = z[v.z >> 10];
        float z3 = z[v.w >> 10];
        atomicAdd(&facc[v.x & 1023u], z0);
        atomicAdd(&facc[v.y & 1023u], z1);
        atomicAdd(&facc[v.z & 1023u], z2);
        atomicAdd(&facc[v.w & 1023u], z3);
    }
    int t = nv * 4 + tid;
    if (t < cnt) { uint32_t p = seg[t]; atomicAdd(&facc[p & 1023u], z[p >> 10]); }
    __syncthreads();
    for (int l = tid; l < CPB; l += 512) {
        int v = b * CPB + l;
        float tt = z[v] + facc[l];
        float d = dinv[v];
        out[v] = mode ? d * d * tt : d * tt;
    }
}

// out[g] = W * mean_{chunk g}(xf) + b
__global__ void pool_kernel(const float* __restrict__ xf,
                            const float* __restrict__ W, const float* __restrict__ b,
                            float* __restrict__ out) {
    __shared__ double sdata[256];
    int g = blockIdx.x;
    int base = g * CHUNK;
    double s = 0.0;
    for (int i = threadIdx.x; i < CHUNK; i += 256) s += (double)xf[base + i];
    sdata[threadIdx.x] = s;
    __syncthreads();
    for (int off = 128; off > 0; off >>= 1) {
        if (threadIdx.x < off) sdata[threadIdx.x] += sdata[threadIdx.x + off];
        __syncthreads();
    }
    if (threadIdx.x == 0)
        out[g] = (float)((double)W[0] * (sdata[0] / (double)CHUNK) + (double)b[0]);
}

// ---------------- fallback (push, atomics) for small ws ---------------------
__device__ __forceinline__ int load_idx(const void* ei, int is64, size_t pos) {
    if (is64) return (int)((const unsigned long long*)ei)[pos];
    return ((const int*)ei)[pos];
}

__global__ void count_kernel(const void* __restrict__ ei, const int* __restrict__ flag,
                             int* __restrict__ deg) {
    int e = blockIdx.x * blockDim.x + threadIdx.x;
    int c = load_idx(ei, flag[0], (size_t)N_EDGES + (size_t)e);
    atomicAdd(&deg[c], 1);
}

__global__ void dinv_kernel(const int* __restrict__ deg, float* __restrict__ dinv) {
    int v = blockIdx.x * blockDim.x + threadIdx.x;
    dinv[v] = (float)(1.0 / sqrt((double)(deg[v] + 1)));
}

__global__ void prep_first2_kernel(const float* __restrict__ x, const float* __restrict__ dinv,
                                   float* __restrict__ z, float* __restrict__ acc) {
    int v = blockIdx.x * blockDim.x + threadIdx.x;
    float t = dinv[v] * x[v];
    z[v] = t;
    acc[v] = t;
}

__global__ void prep_mid_kernel(const float* __restrict__ dinv,
                                float* __restrict__ z, float* __restrict__ acc) {
    int v = blockIdx.x * blockDim.x + threadIdx.x;
    float d = dinv[v];
    float t = d * d * acc[v];
    z[v] = t;
    acc[v] = t;
}

__global__ void push_kernel(const void* __restrict__ ei, const int* __restrict__ flag,
                            const float* __restrict__ z, float* __restrict__ acc) {
    int e = blockIdx.x * blockDim.x + threadIdx.x;
    int is64 = flag[0];
    int r, c;
    if (is64) {
        const unsigned long long* p = (const unsigned long long*)ei;
        r = (int)p[e];
        c = (int)p[(size_t)N_EDGES + (size_t)e];
    } else {
        const int* p = (const int*)ei;
        r = p[e];
        c = p[(size_t)N_EDGES + (size_t)e];
    }
    __hip_atomic_fetch_add(&acc[c], z[r], __ATOMIC_RELAXED, __HIP_MEMORY_SCOPE_AGENT);
}

__global__ void final_scale_kernel(const float* __restrict__ dinv,
                                   const float* __restrict__ acc, float* __restrict__ xf) {
    int v = blockIdx.x * blockDim.x + threadIdx.x;
    xf[v] = dinv[v] * acc[v];
}

extern "C" void kernel_launch(void* const* d_in, const int* in_sizes, int n_in,
                              void* d_out, int out_size, void* d_ws, size_t ws_size,
                              hipStream_t stream) {
    const float* x = (const float*)d_in[0];
    const void*  ei = d_in[1];
    const float* W = (const float*)d_in[2];
    const float* b = (const float*)d_in[3];
    float* out = (float*)d_out;

    char* ws = (char*)d_ws;
    const size_t MB4 = 4ull << 20;
    size_t off_flag   = 0;                                // 256 B
    size_t off_cursor = 256;                              // 4 KB
    size_t off_dinv   = off_cursor + NBUCKET * 4;         // 4 MB
    size_t off_za     = off_dinv + MB4;                   // 4 MB
    size_t off_zb     = off_za + MB4;                     // 4 MB
    size_t off_packed = off_zb + MB4;                     // 72 MB
    size_t needed     = off_packed + (size_t)NBUCKET * CAP * 4;

    const int TB = 256;

    if (ws_size >= needed) {
        int*      flag   = (int*)(ws + off_flag);
        int*      cursor = (int*)(ws + off_cursor);
        float*    dinv   = (float*)(ws + off_dinv);
        float*    za     = (float*)(ws + off_za);
        float*    zb     = (float*)(ws + off_zb);
        uint32_t* packed = (uint32_t*)(ws + off_packed);

        detect_kernel<<<1, TB, 0, stream>>>((const uint32_t*)ei, flag);
        zero_int_kernel<<<NBUCKET / TB, TB, 0, stream>>>(cursor);
        scatter_sort_kernel<<<NBLK_SS, TB_SS, 0, stream>>>(ei, flag, cursor, packed);
        degdinv_kernel<<<NBUCKET, 512, 0, stream>>>(packed, cursor, x, dinv, za);

        hop_kernel<<<NBUCKET, 512, 0, stream>>>(packed, cursor, za, dinv, zb, 1);
        hop_kernel<<<NBUCKET, 512, 0, stream>>>(packed, cursor, zb, dinv, za, 1);
        hop_kernel<<<NBUCKET, 512, 0, stream>>>(packed, cursor, za, dinv, zb, 1);
        hop_kernel<<<NBUCKET, 512, 0, stream>>>(packed, cursor, zb, dinv, za, 0);

        pool_kernel<<<N_GRAPHS, TB, 0, stream>>>(za, W, b, out);
    } else {
        // Fallback: push-based with atomics.
        int*   flag = (int*)ws;
        float* dinv = (float*)(ws + 256);
        float* za   = (float*)(ws + 256 + MB4);
        float* zb   = (float*)(ws + 256 + 2 * MB4);
        int*   deg  = (int*)(ws + 256 + 3 * MB4);

        detect_kernel<<<1, TB, 0, stream>>>((const uint32_t*)ei, flag);
        zero_int_kernel<<<N_NODES / TB, TB, 0, stream>>>(deg);
        count_kernel<<<N_EDGES / TB, TB, 0, stream>>>(ei, flag, deg);
        dinv_kernel<<<N_NODES / TB, TB, 0, stream>>>(deg, dinv);

        prep_first2_kernel<<<N_NODES / TB, TB, 0, stream>>>(x, dinv, za, zb);
        push_kernel<<<N_EDGES / TB, TB, 0, stream>>>(ei, flag, za, zb);
        for (int h = 1; h < K_HOPS; ++h) {
            prep_mid_kernel<<<N_NODES / TB, TB, 0, stream>>>(dinv, za, zb);
            push_kernel<<<N_EDGES / TB, TB, 0, stream>>>(ei, flag, za, zb);
        }
        final_scale_kernel<<<N_NODES / TB, TB, 0, stream>>>(dinv, zb, za);
        pool_kernel<<<N_GRAPHS, TB, 0, stream>>>(za, W, b, out);
    }
}